// Round 1
// baseline (685.435 us; speedup 1.0000x reference)
//
#include <hip/hip_runtime.h>

// FFF binary-tree routing, MI355X — fp32 in/out.
// x[65536,1024] f32, X[1023,1024] f32, Y[1023,1024] f32 -> y[65536,1024] f32.
// One wave per sample; lane l owns elements {c*256 + 4l + j}.
//
// v2: speculative software pipeline. At depth d the two CANDIDATE rows for
// depth d+1 (children 2n+1, 2n+2) are loaded and their per-lane fp64 partial
// dots computed BEFORE the routing sign is known; after the sign arrives we
// select the partial (2 cndmask) and run a single 64-lane butterfly. This
// removes the dependent X-load + FMA-chain latency from the per-depth
// critical path, leaving only select -> butterfly -> scalar branch.
// Y[node] is issued right after the decision and consumed only by the
// latency-tolerant axpy. fp64 dot (4x4 tree) keeps routing-sign fidelity.

constexpr int DEPTH = 10;
constexpr int N_IN  = 1024;
constexpr int N_OUT = 1024;

__device__ __forceinline__ void load_row(float4 (&dst)[4],
                                         const float* __restrict__ base,
                                         int row, int lane)
{
    const float4* p = reinterpret_cast<const float4*>(base + (size_t)row * N_IN) + lane;
#pragma unroll
    for (int c = 0; c < 4; ++c) dst[c] = p[c * 64];
}

// 16-element per-lane fp64 dot, 4 independent chains (4-deep) + 2-level tree.
__device__ __forceinline__ double dot16(const float4 (&a)[4], const float4 (&b)[4])
{
    double p0 = 0.0, p1 = 0.0, p2 = 0.0, p3 = 0.0;
    p0 = fma((double)a[0].x, (double)b[0].x, p0);
    p0 = fma((double)a[0].y, (double)b[0].y, p0);
    p0 = fma((double)a[0].z, (double)b[0].z, p0);
    p0 = fma((double)a[0].w, (double)b[0].w, p0);
    p1 = fma((double)a[1].x, (double)b[1].x, p1);
    p1 = fma((double)a[1].y, (double)b[1].y, p1);
    p1 = fma((double)a[1].z, (double)b[1].z, p1);
    p1 = fma((double)a[1].w, (double)b[1].w, p1);
    p2 = fma((double)a[2].x, (double)b[2].x, p2);
    p2 = fma((double)a[2].y, (double)b[2].y, p2);
    p2 = fma((double)a[2].z, (double)b[2].z, p2);
    p2 = fma((double)a[2].w, (double)b[2].w, p2);
    p3 = fma((double)a[3].x, (double)b[3].x, p3);
    p3 = fma((double)a[3].y, (double)b[3].y, p3);
    p3 = fma((double)a[3].z, (double)b[3].z, p3);
    p3 = fma((double)a[3].w, (double)b[3].w, p3);
    return (p0 + p1) + (p2 + p3);
}

__device__ __forceinline__ double wave_sum64(double p)
{
#pragma unroll
    for (int off = 32; off > 0; off >>= 1)
        p += __shfl_xor(p, off, 64);
    return p;
}

__global__ __launch_bounds__(256) void fff_fwd(
        const float* __restrict__ xg,
        const float* __restrict__ Xg,
        const float* __restrict__ Yg,
        float* __restrict__ outg,
        int n_batch)
{
    const int lane = threadIdx.x & 63;
    const int wave = blockIdx.x * (blockDim.x >> 6) + (threadIdx.x >> 6);
    if (wave >= n_batch) return;

    // ---- this sample's x: 4 coalesced float4 chunks ----
    const float4* xp = reinterpret_cast<const float4*>(xg + (size_t)wave * N_IN) + lane;
    float4 xv[4];
#pragma unroll
    for (int c = 0; c < 4; ++c) xv[c] = xp[c * 64];

    float4 acc[4];
#pragma unroll
    for (int c = 0; c < 4; ++c) acc[c] = make_float4(0.f, 0.f, 0.f, 0.f);

    // ---- prologue: depth 0 (node 0 known statically) + first candidates ----
    float4 cur[4], xl[4], xr[4], yv[4];
    load_row(cur, Xg, 0, lane);   // X[0]
    load_row(xl,  Xg, 1, lane);   // depth-1 candidate L
    load_row(xr,  Xg, 2, lane);   // depth-1 candidate R
    load_row(yv,  Yg, 0, lane);   // Y[0]

    double p = dot16(xv, cur);
    p = wave_sum64(p);
    int   s   = (p > 0.0) ? 1 : 0;
    float lam = (float)p;
#pragma unroll
    for (int c = 0; c < 4; ++c) {
        acc[c].x = fmaf(lam, yv[c].x, acc[c].x);
        acc[c].y = fmaf(lam, yv[c].y, acc[c].y);
        acc[c].z = fmaf(lam, yv[c].z, acc[c].z);
        acc[c].w = fmaf(lam, yv[c].w, acc[c].w);
    }

    // speculative partial dots for depth 1 (both candidates)
    double pl = dot16(xv, xl);
    double pr = dot16(xv, xr);

    int node = __builtin_amdgcn_readfirstlane(1 + s);   // node_1

#pragma unroll
    for (int d = 1; d < DEPTH; ++d) {
        // issue next-depth candidate loads first (addresses need only node_d,
        // not this depth's sign) — one full iteration of latency slack
        if (d < DEPTH - 1) {
            load_row(xl, Xg, 2 * node + 1, lane);
            load_row(xr, Xg, 2 * node + 2, lane);
        }
        load_row(yv, Yg, node, lane);

        // ---- critical path: select speculative partial, one butterfly ----
        p = s ? pr : pl;
        p = wave_sum64(p);
        const int snew = (p > 0.0) ? 1 : 0;
        lam = (float)p;

        // speculative partial dots for depth d+1 (overlap with axpy/scalar)
        if (d < DEPTH - 1) {
            pl = dot16(xv, xl);
            pr = dot16(xv, xr);
        }

        // ---- y += lam * Y[node] (latency-tolerant, off routing path) ----
#pragma unroll
        for (int c = 0; c < 4; ++c) {
            acc[c].x = fmaf(lam, yv[c].x, acc[c].x);
            acc[c].y = fmaf(lam, yv[c].y, acc[c].y);
            acc[c].z = fmaf(lam, yv[c].z, acc[c].z);
            acc[c].w = fmaf(lam, yv[c].w, acc[c].w);
        }

        s = snew;
        node = __builtin_amdgcn_readfirstlane(2 * node + 1 + snew);
    }

    // ---- coalesced float4 store ----
    float4* op = reinterpret_cast<float4*>(outg + (size_t)wave * N_OUT) + lane;
#pragma unroll
    for (int c = 0; c < 4; ++c) op[c * 64] = acc[c];
}

extern "C" void kernel_launch(void* const* d_in, const int* in_sizes, int n_in,
                              void* d_out, int out_size, void* d_ws, size_t ws_size,
                              hipStream_t stream) {
    const float* x = (const float*)d_in[0];
    const float* X = (const float*)d_in[1];
    const float* Y = (const float*)d_in[2];
    float* out = (float*)d_out;

    const int n_batch = in_sizes[0] / N_IN;          // 65536
    const int waves_per_block = 4;                   // 256 threads
    const int blocks = (n_batch + waves_per_block - 1) / waves_per_block;

    fff_fwd<<<blocks, 256, 0, stream>>>(x, X, Y, out, n_batch);
}

// Round 2
// 569.381 us; speedup vs baseline: 1.2038x; 1.2038x over previous
//
#include <hip/hip_runtime.h>

// FFF binary-tree routing, MI355X — fp32 in/out.
// x[65536,1024] f32, X[1023,1024] f32, Y[1023,1024] f32 -> y[65536,1024] f32.
// One wave per sample; lane l owns elements {c*256 + 4l + j}.
//
// v3: the measured regime is L2/vector-memory THROUGHPUT on the X/Y row
// gather (time scales ~linearly at ~50-59 us/GB of row traffic; v2's
// speculative 1.5x traffic ran 1.28x slower). So: cut bytes.
//   - Stage X[0..14] + Y[0..14] (depths 0..3, 120 KB) in LDS once per
//     1024-thread block; 40% of row-gather bytes move to the dedicated
//     LDS pipe and stop competing for L1/L2.
//   - Revert v2's dual speculative dots (they were the traffic regression).
//   - Keep fp64 dot (4 independent chains + tree) for routing-sign fidelity
//     and the fp64 64-lane butterfly (bit-identical on every lane).

constexpr int DEPTH     = 10;
constexpr int N_IN      = 1024;
constexpr int N_OUT     = 1024;
constexpr int LDS_DEPTHS = 4;    // depths 0..3 served from LDS
constexpr int LDS_NODES  = 15;   // 2^4 - 1 rows of X and of Y
constexpr int THREADS    = 1024; // 16 waves/block, 1 block/CU (120 KB LDS)

__device__ __forceinline__ void load_row4(float4 (&dst)[4], const float* __restrict__ row, int lane)
{
    const float4* p = reinterpret_cast<const float4*>(row) + lane;
#pragma unroll
    for (int c = 0; c < 4; ++c) dst[c] = p[c * 64];
}

// 16-element per-lane fp64 dot: 4 independent 4-deep chains + 2-level tree.
__device__ __forceinline__ double dot16(const float4 (&a)[4], const float4 (&b)[4])
{
    double p0 = 0.0, p1 = 0.0, p2 = 0.0, p3 = 0.0;
    p0 = fma((double)a[0].x, (double)b[0].x, p0);
    p0 = fma((double)a[0].y, (double)b[0].y, p0);
    p0 = fma((double)a[0].z, (double)b[0].z, p0);
    p0 = fma((double)a[0].w, (double)b[0].w, p0);
    p1 = fma((double)a[1].x, (double)b[1].x, p1);
    p1 = fma((double)a[1].y, (double)b[1].y, p1);
    p1 = fma((double)a[1].z, (double)b[1].z, p1);
    p1 = fma((double)a[1].w, (double)b[1].w, p1);
    p2 = fma((double)a[2].x, (double)b[2].x, p2);
    p2 = fma((double)a[2].y, (double)b[2].y, p2);
    p2 = fma((double)a[2].z, (double)b[2].z, p2);
    p2 = fma((double)a[2].w, (double)b[2].w, p2);
    p3 = fma((double)a[3].x, (double)b[3].x, p3);
    p3 = fma((double)a[3].y, (double)b[3].y, p3);
    p3 = fma((double)a[3].z, (double)b[3].z, p3);
    p3 = fma((double)a[3].w, (double)b[3].w, p3);
    return (p0 + p1) + (p2 + p3);
}

__device__ __forceinline__ double wave_sum64(double p)
{
#pragma unroll
    for (int off = 32; off > 0; off >>= 1)
        p += __shfl_xor(p, off, 64);
    return p;
}

__global__ __launch_bounds__(THREADS) void fff_fwd(
        const float* __restrict__ xg,
        const float* __restrict__ Xg,
        const float* __restrict__ Yg,
        float* __restrict__ outg,
        int n_batch)
{
    extern __shared__ float lds[];
    float* sX = lds;                         // [15][1024]
    float* sY = lds + LDS_NODES * N_IN;      // [15][1024]

    // ---- cooperative stage of the top tree (depths 0..3) ----
    {
        const float4* gx4 = reinterpret_cast<const float4*>(Xg);
        const float4* gy4 = reinterpret_cast<const float4*>(Yg);
        float4* sx4 = reinterpret_cast<float4*>(sX);
        float4* sy4 = reinterpret_cast<float4*>(sY);
        const int n4 = LDS_NODES * N_IN / 4;          // 3840 float4s each
        for (int i = threadIdx.x; i < n4; i += THREADS) {
            sx4[i] = gx4[i];
            sy4[i] = gy4[i];
        }
    }
    __syncthreads();

    const int lane = threadIdx.x & 63;
    const int wave = blockIdx.x * (THREADS >> 6) + (threadIdx.x >> 6);
    if (wave >= n_batch) return;

    // ---- this sample's x: 4 coalesced float4 chunks ----
    const float4* xp = reinterpret_cast<const float4*>(xg + (size_t)wave * N_IN) + lane;
    float4 xv[4];
#pragma unroll
    for (int c = 0; c < 4; ++c) xv[c] = xp[c * 64];

    float4 acc[4];
#pragma unroll
    for (int c = 0; c < 4; ++c) acc[c] = make_float4(0.f, 0.f, 0.f, 0.f);

    int node = 0;
#pragma unroll
    for (int d = 0; d < DEPTH; ++d) {
        float4 xr[4], yr[4];
        if (d < LDS_DEPTHS) {
            load_row4(xr, sX + node * N_IN, lane);    // LDS pipe
            load_row4(yr, sY + node * N_IN, lane);
        } else {
            load_row4(xr, Xg + (size_t)node * N_IN, lane);
            load_row4(yr, Yg + (size_t)node * N_IN, lane);
        }

        // ---- dot(x, X[node]) in fp64 for routing-sign fidelity ----
        double p = dot16(xv, xr);
        p = wave_sum64(p);                  // bit-identical on all 64 lanes
        const float lam = (float)p;

        // ---- y += lam * Y[node] (fp32, off routing path) ----
#pragma unroll
        for (int c = 0; c < 4; ++c) {
            acc[c].x = fmaf(lam, yr[c].x, acc[c].x);
            acc[c].y = fmaf(lam, yr[c].y, acc[c].y);
            acc[c].z = fmaf(lam, yr[c].z, acc[c].z);
            acc[c].w = fmaf(lam, yr[c].w, acc[c].w);
        }

        // ---- branch (wave-uniform -> scalarize) ----
        const int go_right = (p > 0.0) ? 1 : 0;
        node = __builtin_amdgcn_readfirstlane(node * 2 + 1 + go_right);
    }

    // ---- coalesced float4 store ----
    float4* op = reinterpret_cast<float4*>(outg + (size_t)wave * N_OUT) + lane;
#pragma unroll
    for (int c = 0; c < 4; ++c) op[c * 64] = acc[c];
}

extern "C" void kernel_launch(void* const* d_in, const int* in_sizes, int n_in,
                              void* d_out, int out_size, void* d_ws, size_t ws_size,
                              hipStream_t stream) {
    const float* x = (const float*)d_in[0];
    const float* X = (const float*)d_in[1];
    const float* Y = (const float*)d_in[2];
    float* out = (float*)d_out;

    const int n_batch = in_sizes[0] / N_IN;               // 65536
    const int blocks  = (n_batch + (THREADS >> 6) - 1) / (THREADS >> 6);
    const size_t smem = (size_t)2 * LDS_NODES * N_IN * sizeof(float);  // 120 KB

    static bool attr_set = false;
    if (!attr_set) {
        (void)hipFuncSetAttribute((const void*)fff_fwd,
                                  hipFuncAttributeMaxDynamicSharedMemorySize,
                                  (int)smem);
        attr_set = true;
    }

    fff_fwd<<<blocks, THREADS, smem, stream>>>(x, X, Y, out, n_batch);
}